// Round 3
// baseline (43.495 us; speedup 1.0000x reference)
//
#include <hip/hip_runtime.h>

// AdaptiveVectorQuantizer on MI355X (gfx950).
// input (2,16,64,64,64) fp32 -> 32 images, C=D=64 channels, HW=4096.
// codebook (16,64), prev (16,64), num_active_vectors=16 -> 4 levels {2,4,8,16}.
// Output: quantized (4,32,64,64,64) fp32, losses (4,), codebook[:16].
//
// Cooperative float4 stores. Phase 1: 1 thread/position computes 16 dots +
// prefix argmins, drops idx (u8) into LDS. Phase 2: block writes its
// 4x64x256 output tile as dwordx4 (1KiB/wave-instr), gathering cb rows from
// pad-65 LDS (bank=(idx+c)&31, conflict-free). Stores nontemporal.

namespace {

typedef float f32x4 __attribute__((ext_vector_type(4)));

constexpr int D     = 64;
constexpr int P     = 16;
constexpr int NLEV  = 4;
constexpr int BLOCK = 256;
constexpr int NPOS  = 32 * 4096;      // 131072 positions
constexpr int NBLK  = NPOS / BLOCK;   // 512 blocks

__global__ __launch_bounds__(BLOCK) void avq_main(
    const float* __restrict__ in,
    const float* __restrict__ cb,
    float* __restrict__ out,
    float* __restrict__ partial)
{
  __shared__ float cb_s[P][D + 1];      // pad 65: gather bank=(idx+c)&31
  __shared__ float cb2_s[P];
  __shared__ unsigned char idx_s[NLEV][BLOCK];
  __shared__ float wred[4 * NLEV];

  const int tid = threadIdx.x;
  for (int i = tid; i < P * D; i += BLOCK)
    cb_s[i >> 6][i & 63] = cb[i];
  __syncthreads();
  if (tid < P) {
    float s = 0.f;
    #pragma unroll
    for (int c = 0; c < D; ++c) { const float v = cb_s[tid][c]; s = fmaf(v, v, s); }
    cb2_s[tid] = s;
  }
  __syncthreads();

  const int n      = blockIdx.x >> 4;           // 16 blocks per image
  const int hwbase = (blockIdx.x & 15) << 8;    // 256 positions per block
  const float* __restrict__ src = in + (n << 18) + hwbase + tid;

  float dot[P];
  #pragma unroll
  for (int q = 0; q < P; ++q) dot[q] = 0.f;
  float x2 = 0.f;

  #pragma unroll
  for (int c = 0; c < D; ++c) {
    const float xv = src[c << 12];
    x2 = fmaf(xv, xv, x2);
    #pragma unroll
    for (int q = 0; q < P; ++q) dot[q] = fmaf(xv, cb_s[q][c], dot[q]);
  }

  // rel = cb^2 - 2*dot ; x2 is a common per-row offset -> drop for argmin.
  float rel[P];
  #pragma unroll
  for (int q = 0; q < P; ++q) rel[q] = fmaf(-2.f, dot[q], cb2_s[q]);

  // Prefix argmins over nv={2,4,8,16}; strict < = jnp.argmin tie-break.
  float err[NLEV];
  {
    int bi = 0; float bv = rel[0];
    if (rel[1] < bv) { bv = rel[1]; bi = 1; }
    idx_s[0][tid] = (unsigned char)bi; err[0] = x2 + bv;
    #pragma unroll
    for (int q = 2; q < 4; ++q)  if (rel[q] < bv) { bv = rel[q]; bi = q; }
    idx_s[1][tid] = (unsigned char)bi; err[1] = x2 + bv;
    #pragma unroll
    for (int q = 4; q < 8; ++q)  if (rel[q] < bv) { bv = rel[q]; bi = q; }
    idx_s[2][tid] = (unsigned char)bi; err[2] = x2 + bv;
    #pragma unroll
    for (int q = 8; q < 16; ++q) if (rel[q] < bv) { bv = rel[q]; bi = q; }
    idx_s[3][tid] = (unsigned char)bi; err[3] = x2 + bv;
  }

  // Deterministic per-block loss partials.
  const int lane = tid & 63, wv = tid >> 6;
  #pragma unroll
  for (int l = 0; l < NLEV; ++l) {
    float v = err[l];
    #pragma unroll
    for (int off = 32; off > 0; off >>= 1) v += __shfl_down(v, off, 64);
    if (lane == 0) wred[wv * NLEV + l] = v;
  }
  __syncthreads();   // idx_s + wred ready
  if (tid < NLEV) {
    partial[blockIdx.x * NLEV + tid] =
        wred[0 * NLEV + tid] + wred[1 * NLEV + tid] +
        wred[2 * NLEV + tid] + wred[3 * NLEV + tid];
  }

  // Cooperative vectorized store of the 4 x 64 x 256 output tile.
  // j = tid + it*256 bijects over (l,c,hwq): hwq=j&63, c=(j>>6)&63, l=j>>12.
  // Wave = 64 lanes -> 64 consecutive hw-quads at fixed (l,c): 1KiB/instr.
  float* __restrict__ dstbase = out + (n << 18) + hwbase;
  #pragma unroll 4
  for (int it = 0; it < 64; ++it) {
    const int j   = tid + (it << 8);
    const int hwq = j & 63;
    const int c   = (j >> 6) & 63;
    const int l   = j >> 12;
    const unsigned int pack = ((const unsigned int*)idx_s[l])[hwq];
    f32x4 v;
    v.x = cb_s[pack & 15][c];
    v.y = cb_s[(pack >> 8) & 15][c];
    v.z = cb_s[(pack >> 16) & 15][c];
    v.w = cb_s[(pack >> 24) & 15][c];
    __builtin_nontemporal_store(
        v, (f32x4*)(dstbase + (l << 23) + (c << 12) + (hwq << 2)));
  }
}

__device__ inline float block_sum256(float v, float* sbuf, int tid) {
  #pragma unroll
  for (int off = 32; off > 0; off >>= 1) v += __shfl_down(v, off, 64);
  __syncthreads();
  if ((tid & 63) == 0) sbuf[tid >> 6] = v;
  __syncthreads();
  const float r = sbuf[0] + sbuf[1] + sbuf[2] + sbuf[3];
  __syncthreads();
  return r;
}

__global__ __launch_bounds__(BLOCK) void avq_final(
    const float* __restrict__ partial,
    const float* __restrict__ cb,
    const float* __restrict__ prev,
    float* __restrict__ out)
{
  __shared__ float sbuf[4];
  const int tid = threadIdx.x;
  float* __restrict__ losses = out + (NLEV << 23);   // 33554432
  float* __restrict__ cbout  = losses + NLEV;

  for (int i = tid; i < P * D; i += BLOCK) cbout[i] = cb[i];

  float s0 = 0.f, s1 = 0.f, s2 = 0.f, s3 = 0.f;
  for (int b = tid; b < NBLK; b += BLOCK) {
    s0 += partial[b * NLEV + 0];
    s1 += partial[b * NLEV + 1];
    s2 += partial[b * NLEV + 2];
    s3 += partial[b * NLEV + 3];
  }

  float p1 = 0.f, p2 = 0.f, p3 = 0.f;
  for (int e = tid; e < 8 * D; e += BLOCK) {
    const float dlt = prev[e] - cb[e];
    const float d2  = dlt * dlt;
    const int   r   = e >> 6;
    if (r < 2) p1 += d2;
    if (r < 4) p2 += d2;
    p3 += d2;
  }

  s0 = block_sum256(s0, sbuf, tid);
  s1 = block_sum256(s1, sbuf, tid);
  s2 = block_sum256(s2, sbuf, tid);
  s3 = block_sum256(s3, sbuf, tid);
  p1 = block_sum256(p1, sbuf, tid);
  p2 = block_sum256(p2, sbuf, tid);
  p3 = block_sum256(p3, sbuf, tid);

  if (tid == 0) {
    const float inv = 1.0f / 8388608.0f;               // 1/(M*D)
    const float ql0 = s0 * inv, ql1 = s1 * inv, ql2 = s2 * inv, ql3 = s3 * inv;
    losses[0] = ql0 + 0.1f * ql0;
    losses[1] = ql1 + 0.1f * ql1 + 1.0f * 0.33f * (p1 * (1.0f / 128.0f));
    losses[2] = ql2 + 2.0f * 0.33f * (p2 * (1.0f / 256.0f));
    losses[3] = ql3 + 3.0f * 0.33f * (p3 * (1.0f / 512.0f));
  }
}

}  // namespace

extern "C" void kernel_launch(void* const* d_in, const int* in_sizes, int n_in,
                              void* d_out, int out_size, void* d_ws, size_t ws_size,
                              hipStream_t stream) {
  const float* in   = (const float*)d_in[0];
  const float* cb   = (const float*)d_in[1];
  const float* prev = (const float*)d_in[2];
  float* out     = (float*)d_out;
  float* partial = (float*)d_ws;   // NBLK*NLEV floats = 8 KiB scratch

  avq_main<<<NBLK, BLOCK, 0, stream>>>(in, cb, out, partial);
  avq_final<<<1, BLOCK, 0, stream>>>(partial, cb, prev, out);
}

// Round 4
// 40.280 us; speedup vs baseline: 1.0798x; 1.0798x over previous
//
#include <hip/hip_runtime.h>

// AdaptiveVectorQuantizer on MI355X (gfx950) — split-kernel structure.
// A (avq_assign): 1 thread/position, 16 dots + prefix argmins -> u8 idx per
//   level + per-block loss partials. Traffic 34 MB read / 0.5 MB write.
// B (avq_expand): pure streaming expand. Block b owns one (l,n,c, hw-slab):
//   stages the 16-float codebook column c in LDS, gathers by idx, writes
//   4x16B/thread nontemporal. Block 0 does the loss finalize instead.

namespace {

typedef float f32x4 __attribute__((ext_vector_type(4)));

constexpr int D      = 64;
constexpr int P      = 16;
constexpr int NLEV   = 4;
constexpr int NPOS   = 32 * 4096;               // 131072 positions
constexpr int ABLK   = 64;                      // 1 wave per A-block
constexpr int NBLK_A = NPOS / ABLK;             // 2048
constexpr int BBLK   = 256;
constexpr int QPT    = 4;                       // float4-quads per B-thread
constexpr int NQUAD  = NLEV * NPOS * (D / 4);   // 8,388,608
constexpr int NBLK_B = NQUAD / (BBLK * QPT);    // 8192 (64 quad-rows per (l,n,c))

// ---------------- Kernel A: assignment + loss partials ----------------
__global__ __launch_bounds__(ABLK) void avq_assign(
    const float* __restrict__ in, const float* __restrict__ cb,
    float* __restrict__ partial, unsigned char* __restrict__ idx8)
{
  __shared__ f32x4 cb4_s[P][D / 4];   // unpadded: all reads are broadcasts
  __shared__ float cb2_s[P];

  const int tid = threadIdx.x;
  for (int i = tid; i < P * (D / 4); i += ABLK)
    cb4_s[i >> 4][i & 15] = ((const f32x4*)cb)[i];
  __syncthreads();
  if (tid < P) {
    float s = 0.f;
    #pragma unroll
    for (int j = 0; j < D / 4; ++j) {
      const f32x4 v = cb4_s[tid][j];
      s = fmaf(v.x, v.x, s); s = fmaf(v.y, v.y, s);
      s = fmaf(v.z, v.z, s); s = fmaf(v.w, v.w, s);
    }
    cb2_s[tid] = s;
  }
  __syncthreads();

  const int p  = blockIdx.x * ABLK + tid;
  const int n  = p >> 12;
  const int hw = p & 4095;
  const float* __restrict__ src = in + (n << 18) + hw;   // stride 4096 over c

  float dot[P];
  #pragma unroll
  for (int q = 0; q < P; ++q) dot[q] = 0.f;
  float x2 = 0.f;

  // Accumulation order strictly c-ascending (matches prior passing rounds).
  #pragma unroll
  for (int c4 = 0; c4 < D / 4; ++c4) {
    const float xv0 = src[(c4 * 4 + 0) << 12];
    const float xv1 = src[(c4 * 4 + 1) << 12];
    const float xv2 = src[(c4 * 4 + 2) << 12];
    const float xv3 = src[(c4 * 4 + 3) << 12];
    x2 = fmaf(xv0, xv0, x2); x2 = fmaf(xv1, xv1, x2);
    x2 = fmaf(xv2, xv2, x2); x2 = fmaf(xv3, xv3, x2);
    #pragma unroll
    for (int q = 0; q < P; ++q) {
      const f32x4 cv = cb4_s[q][c4];
      float dq = dot[q];
      dq = fmaf(xv0, cv.x, dq); dq = fmaf(xv1, cv.y, dq);
      dq = fmaf(xv2, cv.z, dq); dq = fmaf(xv3, cv.w, dq);
      dot[q] = dq;
    }
  }

  // rel = cb^2 - 2*dot ; x2 is a common per-row offset -> drop for argmin.
  float rel[P];
  #pragma unroll
  for (int q = 0; q < P; ++q) rel[q] = fmaf(-2.f, dot[q], cb2_s[q]);

  // Prefix argmins over nv={2,4,8,16}; strict < = jnp.argmin tie-break.
  float err[NLEV];
  {
    int bi = 0; float bv = rel[0];
    if (rel[1] < bv) { bv = rel[1]; bi = 1; }
    idx8[0 * NPOS + p] = (unsigned char)bi; err[0] = x2 + bv;
    #pragma unroll
    for (int q = 2; q < 4; ++q)  if (rel[q] < bv) { bv = rel[q]; bi = q; }
    idx8[1 * NPOS + p] = (unsigned char)bi; err[1] = x2 + bv;
    #pragma unroll
    for (int q = 4; q < 8; ++q)  if (rel[q] < bv) { bv = rel[q]; bi = q; }
    idx8[2 * NPOS + p] = (unsigned char)bi; err[2] = x2 + bv;
    #pragma unroll
    for (int q = 8; q < 16; ++q) if (rel[q] < bv) { bv = rel[q]; bi = q; }
    idx8[3 * NPOS + p] = (unsigned char)bi; err[3] = x2 + bv;
  }

  // Single-wave block: shuffle-reduce, lane 0 writes the 4 partials.
  #pragma unroll
  for (int l = 0; l < NLEV; ++l) {
    float v = err[l];
    #pragma unroll
    for (int off = 32; off > 0; off >>= 1) v += __shfl_down(v, off, 64);
    if (tid == 0) partial[blockIdx.x * NLEV + l] = v;
  }
}

// ---------------- Kernel B: expand + (block 0) finalize ----------------
__device__ inline float block_sum256(float v, float* sbuf, int tid) {
  #pragma unroll
  for (int off = 32; off > 0; off >>= 1) v += __shfl_down(v, off, 64);
  __syncthreads();
  if ((tid & 63) == 0) sbuf[tid >> 6] = v;
  __syncthreads();
  const float r = sbuf[0] + sbuf[1] + sbuf[2] + sbuf[3];
  __syncthreads();
  return r;
}

__global__ __launch_bounds__(BBLK) void avq_expand(
    const float* __restrict__ cb, const float* __restrict__ prev,
    const float* __restrict__ partial, const unsigned char* __restrict__ idx8,
    float* __restrict__ out)
{
  __shared__ float col_s[P];
  __shared__ float sbuf[4];
  const int tid = threadIdx.x;

  if (blockIdx.x == 0) {
    // ---- finalize: losses + codebook passthrough ----
    float* __restrict__ losses = out + NQUAD * 4;      // 33,554,432
    float* __restrict__ cbout  = losses + NLEV;
    for (int i = tid; i < P * D; i += BBLK) cbout[i] = cb[i];

    float s0 = 0.f, s1 = 0.f, s2 = 0.f, s3 = 0.f;
    for (int b = tid; b < NBLK_A; b += BBLK) {
      s0 += partial[b * NLEV + 0];
      s1 += partial[b * NLEV + 1];
      s2 += partial[b * NLEV + 2];
      s3 += partial[b * NLEV + 3];
    }
    float p1 = 0.f, p2 = 0.f, p3 = 0.f;
    for (int e = tid; e < 8 * D; e += BBLK) {
      const float dlt = prev[e] - cb[e];
      const float d2  = dlt * dlt;
      const int   r   = e >> 6;
      if (r < 2) p1 += d2;
      if (r < 4) p2 += d2;
      p3 += d2;
    }
    s0 = block_sum256(s0, sbuf, tid);
    s1 = block_sum256(s1, sbuf, tid);
    s2 = block_sum256(s2, sbuf, tid);
    s3 = block_sum256(s3, sbuf, tid);
    p1 = block_sum256(p1, sbuf, tid);
    p2 = block_sum256(p2, sbuf, tid);
    p3 = block_sum256(p3, sbuf, tid);
    if (tid == 0) {
      const float inv = 1.0f / 8388608.0f;             // 1/(M*D)
      const float ql0 = s0 * inv, ql1 = s1 * inv, ql2 = s2 * inv, ql3 = s3 * inv;
      losses[0] = ql0 + 0.1f * ql0;
      losses[1] = ql1 + 0.1f * ql1 + 1.0f * 0.33f * (p1 * (1.0f / 128.0f));
      losses[2] = ql2 + 2.0f * 0.33f * (p2 * (1.0f / 256.0f));
      losses[3] = ql3 + 3.0f * 0.33f * (p3 * (1.0f / 512.0f));
    }
    return;
  }

  // ---- expansion: block b covers one (l,n,c) slab of 1024 quads ----
  const int b  = blockIdx.x - 1;        // 0 .. 8191
  const int ln = b >> 6;                // l*32+n, 0..127
  const int c  = b & 63;

  // Stage codebook column c: col_s[q] = cb[q][c]; gather bank = q (conflict-free).
  if (tid < P) col_s[tid] = cb[tid * D + c];
  __syncthreads();

  const unsigned* __restrict__ packs = (const unsigned*)idx8 + (ln << 10);
  float* __restrict__ dst = out + ((long)b << 12);     // 1024 quads = 4096 floats

  #pragma unroll
  for (int it = 0; it < QPT; ++it) {
    const int hwq = (it << 8) + tid;                   // 0..1023
    const unsigned pack = packs[hwq];
    f32x4 v;
    v.x = col_s[pack & 15];
    v.y = col_s[(pack >> 8) & 15];
    v.z = col_s[(pack >> 16) & 15];
    v.w = col_s[(pack >> 24) & 15];
    __builtin_nontemporal_store(v, (f32x4*)dst + hwq);
  }
}

}  // namespace

extern "C" void kernel_launch(void* const* d_in, const int* in_sizes, int n_in,
                              void* d_out, int out_size, void* d_ws, size_t ws_size,
                              hipStream_t stream) {
  const float* in   = (const float*)d_in[0];
  const float* cb   = (const float*)d_in[1];
  const float* prev = (const float*)d_in[2];
  float* out = (float*)d_out;

  // ws layout: [0, 32KB) loss partials (2048*4 f32), [32KB, 32KB+512KB) idx8.
  float* partial        = (float*)d_ws;
  unsigned char* idx8   = (unsigned char*)d_ws + NBLK_A * NLEV * sizeof(float);

  avq_assign<<<NBLK_A, ABLK, 0, stream>>>(in, cb, partial, idx8);
  avq_expand<<<NBLK_B + 1, BBLK, 0, stream>>>(cb, prev, partial, idx8, out);
}

// Round 5
// 40.025 us; speedup vs baseline: 1.0867x; 1.0064x over previous
//
#include <hip/hip_runtime.h>

// AdaptiveVectorQuantizer on MI355X (gfx950) — split-kernel structure.
// A (avq_assign): 1 thread/position. Round-5 change: stage ALL 64 channel
//   loads into registers before computing (64 loads in flight/wave -> MLP
//   covers ~900cy HBM latency at only 8 waves/CU). FMA order unchanged
//   (strictly c-ascending) -> numerics identical to the passing round.
// B (avq_expand): unchanged. Streaming expand, one (l,n,c) slab per block,
//   16-float codebook column in LDS, 4x16B nontemporal stores/thread.
//   Block 0 does the loss finalize.

namespace {

typedef float f32x4 __attribute__((ext_vector_type(4)));

constexpr int D      = 64;
constexpr int P      = 16;
constexpr int NLEV   = 4;
constexpr int NPOS   = 32 * 4096;               // 131072 positions
constexpr int ABLK   = 64;                      // 1 wave per A-block
constexpr int NBLK_A = NPOS / ABLK;             // 2048
constexpr int BBLK   = 256;
constexpr int QPT    = 4;                       // float4-quads per B-thread
constexpr int NQUAD  = NLEV * NPOS * (D / 4);   // 8,388,608
constexpr int NBLK_B = NQUAD / (BBLK * QPT);    // 8192

// ---------------- Kernel A: assignment + loss partials ----------------
__global__ __launch_bounds__(ABLK) void avq_assign(
    const float* __restrict__ in, const float* __restrict__ cb,
    float* __restrict__ partial, unsigned char* __restrict__ idx8)
{
  __shared__ f32x4 cb4_s[P][D / 4];   // reads are wave-broadcasts
  __shared__ float cb2_s[P];

  const int tid = threadIdx.x;
  for (int i = tid; i < P * (D / 4); i += ABLK)
    cb4_s[i >> 4][i & 15] = ((const f32x4*)cb)[i];
  __syncthreads();
  if (tid < P) {
    float s = 0.f;
    #pragma unroll
    for (int j = 0; j < D / 4; ++j) {
      const f32x4 v = cb4_s[tid][j];
      s = fmaf(v.x, v.x, s); s = fmaf(v.y, v.y, s);
      s = fmaf(v.z, v.z, s); s = fmaf(v.w, v.w, s);
    }
    cb2_s[tid] = s;
  }
  __syncthreads();

  const int p  = blockIdx.x * ABLK + tid;
  const int n  = p >> 12;
  const int hw = p & 4095;
  const float* __restrict__ src = in + (n << 18) + hw;   // stride 4096 over c

  // Stage all channel values first: 64 independent global loads in flight.
  float xv[D];
  #pragma unroll
  for (int c = 0; c < D; ++c) xv[c] = src[c << 12];

  float x2 = 0.f;
  #pragma unroll
  for (int c = 0; c < D; ++c) x2 = fmaf(xv[c], xv[c], x2);

  float dot[P];
  #pragma unroll
  for (int q = 0; q < P; ++q) dot[q] = 0.f;

  // Accumulation strictly c-ascending per q (same numerics as last round).
  #pragma unroll
  for (int c4 = 0; c4 < D / 4; ++c4) {
    #pragma unroll
    for (int q = 0; q < P; ++q) {
      const f32x4 cv = cb4_s[q][c4];
      float dq = dot[q];
      dq = fmaf(xv[c4 * 4 + 0], cv.x, dq);
      dq = fmaf(xv[c4 * 4 + 1], cv.y, dq);
      dq = fmaf(xv[c4 * 4 + 2], cv.z, dq);
      dq = fmaf(xv[c4 * 4 + 3], cv.w, dq);
      dot[q] = dq;
    }
  }

  // rel = cb^2 - 2*dot ; x2 is a common per-row offset -> drop for argmin.
  float rel[P];
  #pragma unroll
  for (int q = 0; q < P; ++q) rel[q] = fmaf(-2.f, dot[q], cb2_s[q]);

  // Prefix argmins over nv={2,4,8,16}; strict < = jnp.argmin tie-break.
  float err[NLEV];
  {
    int bi = 0; float bv = rel[0];
    if (rel[1] < bv) { bv = rel[1]; bi = 1; }
    idx8[0 * NPOS + p] = (unsigned char)bi; err[0] = x2 + bv;
    #pragma unroll
    for (int q = 2; q < 4; ++q)  if (rel[q] < bv) { bv = rel[q]; bi = q; }
    idx8[1 * NPOS + p] = (unsigned char)bi; err[1] = x2 + bv;
    #pragma unroll
    for (int q = 4; q < 8; ++q)  if (rel[q] < bv) { bv = rel[q]; bi = q; }
    idx8[2 * NPOS + p] = (unsigned char)bi; err[2] = x2 + bv;
    #pragma unroll
    for (int q = 8; q < 16; ++q) if (rel[q] < bv) { bv = rel[q]; bi = q; }
    idx8[3 * NPOS + p] = (unsigned char)bi; err[3] = x2 + bv;
  }

  // Single-wave block: shuffle-reduce, lane 0 writes the 4 partials.
  #pragma unroll
  for (int l = 0; l < NLEV; ++l) {
    float v = err[l];
    #pragma unroll
    for (int off = 32; off > 0; off >>= 1) v += __shfl_down(v, off, 64);
    if (tid == 0) partial[blockIdx.x * NLEV + l] = v;
  }
}

// ---------------- Kernel B: expand + (block 0) finalize ----------------
__device__ inline float block_sum256(float v, float* sbuf, int tid) {
  #pragma unroll
  for (int off = 32; off > 0; off >>= 1) v += __shfl_down(v, off, 64);
  __syncthreads();
  if ((tid & 63) == 0) sbuf[tid >> 6] = v;
  __syncthreads();
  const float r = sbuf[0] + sbuf[1] + sbuf[2] + sbuf[3];
  __syncthreads();
  return r;
}

__global__ __launch_bounds__(BBLK) void avq_expand(
    const float* __restrict__ cb, const float* __restrict__ prev,
    const float* __restrict__ partial, const unsigned char* __restrict__ idx8,
    float* __restrict__ out)
{
  __shared__ float col_s[P];
  __shared__ float sbuf[4];
  const int tid = threadIdx.x;

  if (blockIdx.x == 0) {
    // ---- finalize: losses + codebook passthrough ----
    float* __restrict__ losses = out + NQUAD * 4;      // 33,554,432
    float* __restrict__ cbout  = losses + NLEV;
    for (int i = tid; i < P * D; i += BBLK) cbout[i] = cb[i];

    float s0 = 0.f, s1 = 0.f, s2 = 0.f, s3 = 0.f;
    for (int b = tid; b < NBLK_A; b += BBLK) {
      s0 += partial[b * NLEV + 0];
      s1 += partial[b * NLEV + 1];
      s2 += partial[b * NLEV + 2];
      s3 += partial[b * NLEV + 3];
    }
    float p1 = 0.f, p2 = 0.f, p3 = 0.f;
    for (int e = tid; e < 8 * D; e += BBLK) {
      const float dlt = prev[e] - cb[e];
      const float d2  = dlt * dlt;
      const int   r   = e >> 6;
      if (r < 2) p1 += d2;
      if (r < 4) p2 += d2;
      p3 += d2;
    }
    s0 = block_sum256(s0, sbuf, tid);
    s1 = block_sum256(s1, sbuf, tid);
    s2 = block_sum256(s2, sbuf, tid);
    s3 = block_sum256(s3, sbuf, tid);
    p1 = block_sum256(p1, sbuf, tid);
    p2 = block_sum256(p2, sbuf, tid);
    p3 = block_sum256(p3, sbuf, tid);
    if (tid == 0) {
      const float inv = 1.0f / 8388608.0f;             // 1/(M*D)
      const float ql0 = s0 * inv, ql1 = s1 * inv, ql2 = s2 * inv, ql3 = s3 * inv;
      losses[0] = ql0 + 0.1f * ql0;
      losses[1] = ql1 + 0.1f * ql1 + 1.0f * 0.33f * (p1 * (1.0f / 128.0f));
      losses[2] = ql2 + 2.0f * 0.33f * (p2 * (1.0f / 256.0f));
      losses[3] = ql3 + 3.0f * 0.33f * (p3 * (1.0f / 512.0f));
    }
    return;
  }

  // ---- expansion: block b covers one (l,n,c) slab of 1024 quads ----
  const int b  = blockIdx.x - 1;        // 0 .. 8191
  const int ln = b >> 6;                // l*32+n, 0..127
  const int c  = b & 63;

  // Stage codebook column c: col_s[q] = cb[q][c]; gather bank = q.
  if (tid < P) col_s[tid] = cb[tid * D + c];
  __syncthreads();

  const unsigned* __restrict__ packs = (const unsigned*)idx8 + (ln << 10);
  float* __restrict__ dst = out + ((long)b << 12);     // 4096 floats

  #pragma unroll
  for (int it = 0; it < QPT; ++it) {
    const int hwq = (it << 8) + tid;                   // 0..1023
    const unsigned pack = packs[hwq];
    f32x4 v;
    v.x = col_s[pack & 15];
    v.y = col_s[(pack >> 8) & 15];
    v.z = col_s[(pack >> 16) & 15];
    v.w = col_s[(pack >> 24) & 15];
    __builtin_nontemporal_store(v, (f32x4*)dst + hwq);
  }
}

}  // namespace

extern "C" void kernel_launch(void* const* d_in, const int* in_sizes, int n_in,
                              void* d_out, int out_size, void* d_ws, size_t ws_size,
                              hipStream_t stream) {
  const float* in   = (const float*)d_in[0];
  const float* cb   = (const float*)d_in[1];
  const float* prev = (const float*)d_in[2];
  float* out = (float*)d_out;

  // ws layout: [0, 32KB) loss partials (2048*4 f32), then 512KB idx8.
  float* partial      = (float*)d_ws;
  unsigned char* idx8 = (unsigned char*)d_ws + NBLK_A * NLEV * sizeof(float);

  avq_assign<<<NBLK_A, ABLK, 0, stream>>>(in, cb, partial, idx8);
  avq_expand<<<NBLK_B + 1, BBLK, 0, stream>>>(cb, prev, partial, idx8, out);
}